// Round 8
// baseline (1280.257 us; speedup 1.0000x reference)
//
#include <hip/hip_runtime.h>
#include <math.h>

#define N1 1024
#define NN2 (N1*N1)
#define LL 16384
#define PSTR 40  // LDS k-stride in bf16 elems (80 B): 2-way bank aliasing only

typedef unsigned short u16;
typedef __attribute__((ext_vector_type(8))) short bffrag;   // 8 bf16 = 4 VGPR
typedef __attribute__((ext_vector_type(4))) float f32x4;

// ---- bf16 split helpers (RNE, Dekker-exact residual) ----
__device__ __forceinline__ u16 bf16rne(float x, float& rem) {
    unsigned u = __float_as_uint(x);
    u16 h = (u16)((u + 0x7FFF + ((u >> 16) & 1)) >> 16);
    rem = x - __uint_as_float((unsigned)h << 16);
    return h;
}
__device__ __forceinline__ void split3(float x, u16& h0, u16& h1, u16& h2) {
    float r1, r2, r3;
    h0 = bf16rne(x, r1);
    h1 = bf16rne(r1, r2);
    h2 = bf16rne(r2, r3);
}

// ---------------- chain-partial device code (mode 0 = Q rows, 1 = P cols) --------
__device__ __forceinline__ void chain_part(const float* __restrict__ M,
                                           float* __restrict__ V,
                                           float* __restrict__ CP,
                                           int w, int lkc, int mode, int cb,
                                           float* sV, float (*red)[64]) {
    int kc = 1 << lkc;
    int i = cb >> (4 + lkc);
    int ky = (cb >> 4) & (kc - 1);
    int nx = cb & 15;
    int mlen = N1 >> lkc;
    int m0 = ky * mlen, n0 = nx * 64;
    int t = threadIdx.x;
    const float* Vi = V + (size_t)i * N1 + m0;
    if (t * 4 < mlen) *(float4*)&sV[t * 4] = *(const float4*)&Vi[t * 4];
    __syncthreads();
    int wave = t >> 6, lane = t & 63;
    if (mode == 0) {
        for (int rr = 0; rr < 16; ++rr) {
            int n = n0 + wave * 16 + rr;
            const float* Mr = M + (size_t)n * N1 + m0;
            float acc = 0.f;
            for (int m = lane * 4; m < mlen; m += 256) {
                float4 a = *(const float4*)&Mr[m];
                float4 v = *(const float4*)&sV[m];
                acc += a.x * v.x + a.y * v.y + a.z * v.z + a.w * v.w;
            }
#pragma unroll
            for (int off = 32; off > 0; off >>= 1) acc += __shfl_down(acc, off, 64);
            if (lane == 0) {
                if (kc == 1) V[(size_t)(w + i) * N1 + n] = sV[n] + acc;
                else CP[((size_t)i * kc + ky) * N1 + n] = acc;
            }
        }
    } else {
        int n = n0 + lane;
        int msub = mlen >> 2;
        int mb = wave * msub;
        float acc = 0.f;
#pragma unroll 8
        for (int m = 0; m < msub; ++m)
            acc += sV[mb + m] * M[(size_t)(m0 + mb + m) * N1 + n];
        red[wave][lane] = acc;
        __syncthreads();
        if (t < 64) {
            float s = red[0][t] + red[1][t] + red[2][t] + red[3][t];
            if (kc == 1) V[(size_t)(w + i) * N1 + n0 + t] = sV[n0 + t] + s;
            else CP[((size_t)i * kc + ky) * N1 + n0 + t] = s;
        }
    }
}

// ---------------- MFMA GEMM (bf16x3 exact-split), fused with chain blocks --------
// part[z] = A[:, z*512:(z+1)*512] @ B[...]  via 6-term plane products.
// RA: 3 planes [p][m][k] of A (bf16). TB: 3 planes [p][n][k] of B^T (bf16).
// 64x64 tile/block, 4 waves, each wave a 32x32 quadrant (2x2 MFMA tiles).
__global__ __launch_bounds__(256, 1) void k_mfma(const u16* __restrict__ RA,
                                                 const u16* __restrict__ TB,
                                                 float* __restrict__ part,
                                                 const float* __restrict__ Dm,
                                                 float* __restrict__ V,
                                                 float* __restrict__ CP,
                                                 int w, int lkc, int nchain, int mode) {
    __shared__ u16 Asl[3][64][PSTR];
    __shared__ u16 Bsl[3][64][PSTR];
    __shared__ float sV[N1];
    __shared__ float red[4][64];
    int b = blockIdx.x;
    if (b < nchain) {
        chain_part(Dm, V, CP, w, lkc, mode, b, sV, red);
        return;
    }
    int g = b - nchain;
    int t = threadIdx.x;
    int z = g >> 8;                       // split-K slice (0..1), K=512 each
    int ty = (g >> 4) & 15, tx = g & 15;  // 16x16 tile grid
    int m0 = ty * 64, n0 = tx * 64, kz = z * 512;
    int srow = t >> 2, sk = (t & 3) * 8;  // staging: row 0..63, k-chunk of 8
    int wave = t >> 6, lane = t & 63;
    int mq = (wave & 1) * 32, nq = (wave >> 1) * 32;
    int fl = lane & 15, kg8 = (lane >> 4) * 8;

    const size_t abase = (size_t)(m0 + srow) * N1 + kz + sk;
    const size_t bbase = (size_t)(n0 + srow) * N1 + kz + sk;

    uint4 pa[3], pb[3];
#pragma unroll
    for (int p = 0; p < 3; ++p) {
        pa[p] = *(const uint4*)&RA[(size_t)p * NN2 + abase];
        pb[p] = *(const uint4*)&TB[(size_t)p * NN2 + bbase];
    }

    f32x4 acc[2][2];
#pragma unroll
    for (int mi = 0; mi < 2; ++mi)
#pragma unroll
        for (int nj = 0; nj < 2; ++nj) acc[mi][nj] = (f32x4){0.f, 0.f, 0.f, 0.f};

    for (int kt = 0; kt < 16; ++kt) {
#pragma unroll
        for (int p = 0; p < 3; ++p) {
            *(uint4*)&Asl[p][srow][sk] = pa[p];
            *(uint4*)&Bsl[p][srow][sk] = pb[p];
        }
        __syncthreads();
        if (kt < 15) {
            size_t koff = (size_t)(kt + 1) * 32;
#pragma unroll
            for (int p = 0; p < 3; ++p) {
                pa[p] = *(const uint4*)&RA[(size_t)p * NN2 + abase + koff];
                pb[p] = *(const uint4*)&TB[(size_t)p * NN2 + bbase + koff];
            }
        }
        bffrag a[2][3], bb[2][3];
#pragma unroll
        for (int mi = 0; mi < 2; ++mi)
#pragma unroll
            for (int p = 0; p < 3; ++p)
                a[mi][p] = *(bffrag*)&Asl[p][mq + mi * 16 + fl][kg8];
#pragma unroll
        for (int nj = 0; nj < 2; ++nj)
#pragma unroll
            for (int q = 0; q < 3; ++q)
                bb[nj][q] = *(bffrag*)&Bsl[q][nq + nj * 16 + fl][kg8];
#pragma unroll
        for (int mi = 0; mi < 2; ++mi)
#pragma unroll
            for (int nj = 0; nj < 2; ++nj) {
                acc[mi][nj] = __builtin_amdgcn_mfma_f32_16x16x32_bf16(a[mi][0], bb[nj][0], acc[mi][nj], 0, 0, 0);
                acc[mi][nj] = __builtin_amdgcn_mfma_f32_16x16x32_bf16(a[mi][0], bb[nj][1], acc[mi][nj], 0, 0, 0);
                acc[mi][nj] = __builtin_amdgcn_mfma_f32_16x16x32_bf16(a[mi][1], bb[nj][0], acc[mi][nj], 0, 0, 0);
                acc[mi][nj] = __builtin_amdgcn_mfma_f32_16x16x32_bf16(a[mi][0], bb[nj][2], acc[mi][nj], 0, 0, 0);
                acc[mi][nj] = __builtin_amdgcn_mfma_f32_16x16x32_bf16(a[mi][1], bb[nj][1], acc[mi][nj], 0, 0, 0);
                acc[mi][nj] = __builtin_amdgcn_mfma_f32_16x16x32_bf16(a[mi][2], bb[nj][0], acc[mi][nj], 0, 0, 0);
            }
        __syncthreads();
    }
    // epilogue: C/D layout col=lane&15, row=(lane>>4)*4+r
    float* Po = part + (size_t)z * NN2;
#pragma unroll
    for (int mi = 0; mi < 2; ++mi)
#pragma unroll
        for (int nj = 0; nj < 2; ++nj) {
            int row0 = m0 + mq + mi * 16 + (lane >> 4) * 4;
            int col = n0 + nq + nj * 16 + fl;
#pragma unroll
            for (int r = 0; r < 4; ++r)
                Po[(size_t)(row0 + r) * N1 + col] = acc[mi][nj][r];
        }
}

// ---------------- chain-partial-only dispatch ----------------
__global__ __launch_bounds__(256) void k_cpart(const float* __restrict__ M,
                                               float* __restrict__ V,
                                               float* __restrict__ CP,
                                               int w, int lkc, int mode) {
    __shared__ float sV[N1];
    __shared__ float red[4][64];
    chain_part(M, V, CP, w, lkc, mode, blockIdx.x, sV, red);
}

// ---------------- splitter: X = a*in1 + in2 (opt); emit fp32 + R/T bf16 planes ----
// grid 1024 (32x32 tiles), a = c1 * (logd ? exp(logd[0]) : 1)
__global__ __launch_bounds__(256) void k_split(const float* __restrict__ in1,
                                               const float* __restrict__ in2,
                                               const float* __restrict__ logd,
                                               float c1,
                                               float* __restrict__ outX,
                                               u16* __restrict__ Rp,
                                               u16* __restrict__ Tp) {
    __shared__ float tile[32][33];
    int b = blockIdx.x, t = threadIdx.x;
    int bx = b & 31, by = b >> 5;
    int x0 = bx * 32, y0 = by * 32;
    int r = t >> 3, c4 = (t & 7) * 4;
    float a = c1 * (logd ? expf(logd[0]) : 1.f);
    size_t idx = (size_t)(y0 + r) * N1 + x0 + c4;
    float4 v1 = *(const float4*)&in1[idx];
    float4 X;
    X.x = a * v1.x; X.y = a * v1.y; X.z = a * v1.z; X.w = a * v1.w;
    if (in2) {
        float4 v2 = *(const float4*)&in2[idx];
        X.x += v2.x; X.y += v2.y; X.z += v2.z; X.w += v2.w;
    }
    *(float4*)&outX[idx] = X;
    ushort4 h0, h1, h2;
    split3(X.x, h0.x, h1.x, h2.x);
    split3(X.y, h0.y, h1.y, h2.y);
    split3(X.z, h0.z, h1.z, h2.z);
    split3(X.w, h0.w, h1.w, h2.w);
    *(ushort4*)&Rp[idx] = h0;
    *(ushort4*)&Rp[(size_t)NN2 + idx] = h1;
    *(ushort4*)&Rp[2 * (size_t)NN2 + idx] = h2;
    tile[r][c4 + 0] = X.x; tile[r][c4 + 1] = X.y;
    tile[r][c4 + 2] = X.z; tile[r][c4 + 3] = X.w;
    __syncthreads();
    if (Tp) {
        int n = t >> 3, mb = (t & 7) * 4;
        ushort4 g0, g1, g2;
        float xv0 = tile[mb + 0][n], xv1 = tile[mb + 1][n];
        float xv2 = tile[mb + 2][n], xv3 = tile[mb + 3][n];
        split3(xv0, g0.x, g1.x, g2.x);
        split3(xv1, g0.y, g1.y, g2.y);
        split3(xv2, g0.z, g1.z, g2.z);
        split3(xv3, g0.w, g1.w, g2.w);
        size_t tidx = (size_t)(x0 + n) * N1 + y0 + mb;
        *(ushort4*)&Tp[tidx] = g0;
        *(ushort4*)&Tp[(size_t)NN2 + tidx] = g1;
        *(ushort4*)&Tp[2 * (size_t)NN2 + tidx] = g2;
    }
}

// ---------------- fused reduce+split: [1024 tile blocks | 4w chainR blocks] -------
// X = alpha*(MP0+MP1) + beta*Aadd ; write fp32 C + R/T planes; chainR appended.
__global__ __launch_bounds__(256) void k_redusplit(const float* __restrict__ part,
                                                   const float* __restrict__ Aadd,
                                                   float* __restrict__ C,
                                                   float alpha, float beta,
                                                   u16* __restrict__ Rp,
                                                   u16* __restrict__ Tp,
                                                   float* __restrict__ V,
                                                   const float* __restrict__ CP,
                                                   int w, int kc) {
    __shared__ float tile[32][33];
    int b = blockIdx.x, t = threadIdx.x;
    if (b < 1024) {
        int bx = b & 31, by = b >> 5;
        int x0 = bx * 32, y0 = by * 32;
        int r = t >> 3, c4 = (t & 7) * 4;
        size_t idx = (size_t)(y0 + r) * N1 + x0 + c4;
        float4 p0 = *(const float4*)&part[idx];
        float4 p1 = *(const float4*)&part[(size_t)NN2 + idx];
        float4 av = *(const float4*)&Aadd[idx];
        float4 X;
        X.x = alpha * (p0.x + p1.x) + beta * av.x;
        X.y = alpha * (p0.y + p1.y) + beta * av.y;
        X.z = alpha * (p0.z + p1.z) + beta * av.z;
        X.w = alpha * (p0.w + p1.w) + beta * av.w;
        *(float4*)&C[idx] = X;
        ushort4 h0, h1, h2;
        split3(X.x, h0.x, h1.x, h2.x);
        split3(X.y, h0.y, h1.y, h2.y);
        split3(X.z, h0.z, h1.z, h2.z);
        split3(X.w, h0.w, h1.w, h2.w);
        *(ushort4*)&Rp[idx] = h0;
        *(ushort4*)&Rp[(size_t)NN2 + idx] = h1;
        *(ushort4*)&Rp[2 * (size_t)NN2 + idx] = h2;
        tile[r][c4 + 0] = X.x; tile[r][c4 + 1] = X.y;
        tile[r][c4 + 2] = X.z; tile[r][c4 + 3] = X.w;
        __syncthreads();
        int n = t >> 3, mb = (t & 7) * 4;
        ushort4 g0, g1, g2;
        float xv0 = tile[mb + 0][n], xv1 = tile[mb + 1][n];
        float xv2 = tile[mb + 2][n], xv3 = tile[mb + 3][n];
        split3(xv0, g0.x, g1.x, g2.x);
        split3(xv1, g0.y, g1.y, g2.y);
        split3(xv2, g0.z, g1.z, g2.z);
        split3(xv3, g0.w, g1.w, g2.w);
        size_t tidx = (size_t)(x0 + n) * N1 + y0 + mb;
        *(ushort4*)&Tp[tidx] = g0;
        *(ushort4*)&Tp[(size_t)NN2 + tidx] = g1;
        *(ushort4*)&Tp[2 * (size_t)NN2 + tidx] = g2;
    } else {
        int rb = b - 1024;
        int i = rb >> 2;
        int n = (rb & 3) * 256 + t;
        const float* pp = CP + (size_t)i * kc * N1 + n;
        float s = 0.f;
        for (int c = 0; c < kc; ++c) s += pp[(size_t)c * N1];
        V[(size_t)(w + i) * N1 + n] = V[(size_t)i * N1 + n] + s;
    }
}

// ---------------- init reduce: Q[0] = d*(B + 0.5*D1@B); P[0] = C ----------------
__global__ __launch_bounds__(256) void k_initR(const float* __restrict__ Bv,
                                               const float* __restrict__ Cv,
                                               const float* __restrict__ logd,
                                               const float* __restrict__ part,
                                               float* __restrict__ Q,
                                               float* __restrict__ P) {
    int n = blockIdx.x * 256 + threadIdx.x;
    float s = 0.f;
    for (int c = 0; c < 16; ++c) s += part[(size_t)c * N1 + n];
    float d = expf(logd[0]);
    Q[n] = d * (Bv[n] + 0.5f * s);
    P[n] = Cv[n];
}

// ---------------- K[a*128+b] = dot(P[a], Q[b]) ----------------
__global__ __launch_bounds__(256) void k_kdot(const float* __restrict__ P,
                                              const float* __restrict__ Q,
                                              float* __restrict__ K) {
    int t = threadIdx.x;
    int wid = blockIdx.x * 4 + (t >> 6), lane = t & 63;
    int a = wid >> 7, b = wid & 127;
    const float* Pr = P + (size_t)a * N1;
    const float* Qr = Q + (size_t)b * N1;
    float acc = 0.f;
#pragma unroll
    for (int jj = 0; jj < 4; ++jj) {
        int m = jj * 256 + lane * 4;
        float4 p = *(const float4*)&Pr[m];
        float4 q = *(const float4*)&Qr[m];
        acc += p.x * q.x + p.y * q.y + p.z * q.z + p.w * q.w;
    }
#pragma unroll
    for (int off = 32; off > 0; off >>= 1) acc += __shfl_down(acc, off, 64);
    if (lane == 0) K[wid] = acc;
}

// ---------------- conv phase 1 ----------------
__global__ __launch_bounds__(256) void k_conv1(const float* __restrict__ X,
                                               const float* __restrict__ K,
                                               float* __restrict__ part) {
    __shared__ __align__(16) float ks[1280];
    __shared__ __align__(16) float xs[256];
    int bx = blockIdx.x, tt = threadIdx.x;
    int o = 0;
    while (bx >= 2 * (o + 1) * (o + 1) + 2 * (o + 1)) ++o;
    int jt = bx - (2 * o * o + 2 * o);
    int T0 = o * 1024, J0 = jt * 256;
    int mb = T0 - J0 - 255;
    for (int ii = tt; ii < 1280; ii += 256) {
        int m = mb + ii;
        ks[ii] = (m >= 0 && m < LL) ? K[m] : 0.f;
    }
    xs[tt] = X[J0 + tt];
    __syncthreads();

    float acc0 = 0.f, acc1 = 0.f, acc2 = 0.f, acc3 = 0.f;
    int base0 = 4 * tt + 252;
#pragma unroll 4
    for (int jj = 0; jj < 256; jj += 4) {
        float4 xv  = *(const float4*)&xs[jj];
        float4 kv0 = *(const float4*)&ks[base0 - jj];
        float4 kv1 = *(const float4*)&ks[base0 - jj + 4];
        float kk0 = kv0.x, kk1 = kv0.y, kk2 = kv0.z, kk3 = kv0.w;
        float kk4 = kv1.x, kk5 = kv1.y, kk6 = kv1.z;
        acc0 += kk3 * xv.x + kk2 * xv.y + kk1 * xv.z + kk0 * xv.w;
        acc1 += kk4 * xv.x + kk3 * xv.y + kk2 * xv.z + kk1 * xv.w;
        acc2 += kk5 * xv.x + kk4 * xv.y + kk3 * xv.z + kk2 * xv.w;
        acc3 += kk6 * xv.x + kk5 * xv.y + kk4 * xv.z + kk3 * xv.w;
    }
    float4 out = {acc0, acc1, acc2, acc3};
    *(float4*)&part[((size_t)(o * 64 + jt)) * 1024 + 4 * tt] = out;
}

// ---------------- conv phase 2 ----------------
__global__ __launch_bounds__(256) void k_conv2(const float* __restrict__ X,
                                               const float* __restrict__ part,
                                               const float* __restrict__ Dp,
                                               float* __restrict__ Y) {
    int o = blockIdx.x, tt = threadIdx.x;
    int c = 4 * tt;
    float s0 = 0.f, s1 = 0.f, s2 = 0.f, s3 = 0.f;
    int cnt = 4 * o + 4;
    for (int jt = 0; jt < cnt; ++jt) {
        float4 p = *(const float4*)&part[((size_t)(o * 64 + jt)) * 1024 + c];
        s0 += p.x; s1 += p.y; s2 += p.z; s3 += p.w;
    }
    float dsk = Dp[0];
    int t = o * 1024 + c;
    float4 xv = *(const float4*)&X[t];
    float4 out;
    out.x = dsk * xv.x + s0;
    out.y = dsk * xv.y + s1;
    out.z = dsk * xv.z + s2;
    out.w = dsk * xv.w + s3;
    *(float4*)&Y[t] = out;
}

extern "C" void kernel_launch(void* const* d_in, const int* in_sizes, int n_in,
                              void* d_out, int out_size, void* d_ws, size_t ws_size,
                              hipStream_t stream) {
    const float* X    = (const float*)d_in[0];
    const float* A    = (const float*)d_in[1];
    const float* Bv   = (const float*)d_in[2];
    const float* Cv   = (const float*)d_in[3];
    const float* Dp   = (const float*)d_in[4];
    const float* logd = (const float*)d_in[5];
    float* ws = (float*)d_ws;

    float* S0 = ws;                 // e, D ping-pong
    float* S1 = ws + (size_t)NN2;   // e2
    float* S2 = ws + 2*(size_t)NN2; // e^2+e^4
    float* S3 = ws + 3*(size_t)NN2; // t1
    float* S4 = ws + 4*(size_t)NN2; // D1, ping-pong
    float* MP = ws + 5*(size_t)NN2; // 2x NN2 GEMM partials; conv partials
    float* CPb = ws + 7*(size_t)NN2;        // chain partials (<=64 KB)
    float* Qv = CPb + 64*(size_t)N1;        // 128 x 1024
    float* Pv = Qv + 128*(size_t)N1;        // 128 x 1024
    float* Kc = Pv + 128*(size_t)N1;        // 16384
    u16*   R0 = (u16*)(Kc + LL);            // 3 planes A (row-major)
    u16*   R1 = R0 + 3*(size_t)NN2;         // 3 planes (t1)
    u16*   T0 = R1 + 3*(size_t)NN2;         // 3 planes B^T
    float* Y  = (float*)d_out;

    // e = (d/2)A, planes(e)
    k_split<<<1024, 256, 0, stream>>>(A, nullptr, logd, 0.5f, S0, R0, T0);
    // e^2
    k_mfma<<<512, 256, 0, stream>>>(R0, T0, MP, nullptr, nullptr, nullptr, 0, 0, 0, 0);
    k_redusplit<<<1024, 256, 0, stream>>>(MP, S0, S1, 1.f, 0.f, R0, T0, nullptr, nullptr, 0, 1);
    // S2 = e^2 + e^4
    k_mfma<<<512, 256, 0, stream>>>(R0, T0, MP, nullptr, nullptr, nullptr, 0, 0, 0, 0);
    k_redusplit<<<1024, 256, 0, stream>>>(MP, S1, S2, 1.f, 1.f, R0, T0, nullptr, nullptr, 0, 1);
    // t1 = e + e^2 (R-planes only)
    k_split<<<1024, 256, 0, stream>>>(S1, S0, nullptr, 1.f, S3, R1, nullptr);
    // D1 = 2*t1*S2 + 2*t1
    k_mfma<<<512, 256, 0, stream>>>(R1, T0, MP, nullptr, nullptr, nullptr, 0, 0, 0, 0);
    k_redusplit<<<1024, 256, 0, stream>>>(MP, S3, S4, 2.f, 2.f, R0, T0, nullptr, nullptr, 0, 1);

    // init: Q[0] = d*(B + 0.5*D1@B); P[0] = C
    k_cpart<<<256, 256, 0, stream>>>(S4, (float*)Bv, CPb, 1, 4, 0);
    k_initR<<<4, 256, 0, stream>>>(Bv, Cv, logd, CPb, Qv, Pv);

    float* cur = S4;
    float* nxt = S0;
    // Q loop: chain step w=2^k with D_{2^k}, fused with squaring -> D_{2^{k+1}}
    for (int k = 0; k < 7; ++k) {
        int w = 1 << k;
        int lkc = (w < 16) ? (4 - k) : 0;
        int kc = 1 << lkc;
        int nchain = 16 * kc * w;
        int nR = (kc > 1) ? 4 * w : 0;
        k_mfma<<<nchain + 512, 256, 0, stream>>>(R0, T0, MP, cur, Qv, CPb, w, lkc, nchain, 0);
        k_redusplit<<<1024 + nR, 256, 0, stream>>>(MP, cur, nxt, 1.f, 2.f, R0, T0, Qv, CPb, w, kc);
        float* tsw = cur; cur = nxt; nxt = tsw;
    }
    // P loop: k=0..5 fused with squarings (D_128..D_4096 -> D_8192)
    for (int k = 0; k < 6; ++k) {
        int w = 1 << k;
        int lkc = (w < 16) ? (4 - k) : 0;
        int kc = 1 << lkc;
        int nchain = 16 * kc * w;
        int nR = (kc > 1) ? 4 * w : 0;
        k_mfma<<<nchain + 512, 256, 0, stream>>>(R0, T0, MP, cur, Pv, CPb, w, lkc, nchain, 1);
        k_redusplit<<<1024 + nR, 256, 0, stream>>>(MP, cur, nxt, 1.f, 2.f, R0, T0, Pv, CPb, w, kc);
        float* tsw = cur; cur = nxt; nxt = tsw;
    }
    // final P step: w=64 with D_8192, direct write
    k_cpart<<<1024, 256, 0, stream>>>(cur, Pv, CPb, 64, 0, 1);

    k_kdot<<<4096, 256, 0, stream>>>(Pv, Qv, Kc);
    k_conv1<<<544, 256, 0, stream>>>(X, Kc, MP);
    k_conv2<<<16, 256, 0, stream>>>(X, MP, Dp, Y);
}